// Round 3
// 500.378 us; speedup vs baseline: 1.0331x; 1.0331x over previous
//
#include <hip/hip_runtime.h>
#include <hip/hip_bf16.h>

// ActLayer: out[b,o] = sum_{i,f} norm(sin(w_f x[b,i] + p_f)) * beta[f,o] * lamb[i,o] + bias[o]
//
// Round-5: register-sin A-path with the round-0-proven skeleton everywhere else.
// Deltas vs the verified 517us kernel are EXACTLY:
//   1. Wave geometry 16 rows x 128 cols (4 waves cover BM=64): each lane's MFMA
//      A-fragment elements A[l15][kk*32+quad*8+j] are sin values computed by that
//      same lane from 16 x-floats in registers (cvt_pk -> short8 -> MFMA, the
//      HW-proven T12 path). A_sh and its staging are deleted.
//   2. lf/oacc widened to 8 n-tiles per wave (16x128 strip).
// Everything else is verbatim round-0: per-f __syncthreads() cadence, bf16 brP
// [F][16][12] + ushort4t reads, wrev/prev float arrays, union-based packing,
// L_sh staging, prologue, epilogue mapping.
//
// B=8192, I=512, F=64, O=512. BM=64, BN=128, i-chunk 64 (one f per K-step).
// 256 threads = 4 waves, mfma 16x16x32 bf16. Grid = 512 -> 2 blocks/CU.
// LDS ~45.6 KB, VGPR ~170 (2 waves/SIMD ok).

#define TB 256

typedef __attribute__((ext_vector_type(8))) short short8;
typedef __attribute__((ext_vector_type(4))) float floatx4;
typedef __attribute__((ext_vector_type(4))) unsigned int uintx4;
typedef __attribute__((ext_vector_type(4))) unsigned short ushort4t;

__device__ __forceinline__ unsigned pk_bf16(float a, float b) {
    __hip_bfloat162 h = __float22bfloat162_rn(make_float2(a, b));
    union { __hip_bfloat162 h2; unsigned u; } cv; cv.h2 = h; return cv.u;
}
__device__ __forceinline__ unsigned short f_to_bf16u(float v) {
    union { __hip_bfloat16 h; unsigned short u; } cv;
    cv.h = __float2bfloat16(v);
    return cv.u;
}
__device__ __forceinline__ float bf16u_to_f(unsigned short v) {
    union { unsigned u; float f; } cv; cv.u = ((unsigned)v) << 16; return cv.f;
}

// 8 bf16 sin values: sin(2*pi*(x*wfr + pfr)) for 8 register-resident x values.
__device__ __forceinline__ short8 sin_frag8(const float xv[8], float wfr, float pfr) {
    float s[8];
    #pragma unroll
    for (int j = 0; j < 8; ++j) {
        float arg = __builtin_amdgcn_fractf(fmaf(xv[j], wfr, pfr));
        s[j] = __builtin_amdgcn_sinf(arg);
    }
    union { uintx4 u; short8 h; } cv;
    cv.u.x = pk_bf16(s[0], s[1]); cv.u.y = pk_bf16(s[2], s[3]);
    cv.u.z = pk_bf16(s[4], s[5]); cv.u.w = pk_bf16(s[6], s[7]);
    return cv.h;
}

__global__ __launch_bounds__(TB, 2)
void actlayer_kernel(const float* __restrict__ x,
                     const float* __restrict__ freqs,
                     const float* __restrict__ phases,
                     const float* __restrict__ beta,
                     const float* __restrict__ lamb,
                     const float* __restrict__ bias,
                     float* __restrict__ out)
{
    constexpr int I = 512, F = 64, O = 512;
    constexpr int BN = 128;
    const int t  = threadIdx.x;
    const int bx = blockIdx.x;
    const int bn = bx & 3;            // 0..3
    const int bm = bx >> 2;           // 0..127
    const int n0 = bn * BN;
    const int m0 = bm * 64;

    // pad 72 shorts = 144 B rows: 16B-aligned for b128 everywhere
    __shared__ __align__(16) unsigned short L_sh[BN][72];      // lambda tile (bf16), per i-tile
    __shared__ __align__(16) unsigned short brP_sh[F][16][12]; // betaR bf16: [f][c=o%16][w=o/16]
    __shared__ float wrev_sh[F], prev_sh[F], r_sh[F], m_sh[F];
    __shared__ float c_sh[BN];
    __shared__ float slp_sh[2][BN];

    // ---- prologue: per-f normalization constants (verbatim round-0) ----
    if (t < F) {
        float wq = freqs[t];
        float ph = phases[t];
        float e1 = expf(-0.5f * wq * wq);
        float mean = e1 * sinf(ph);
        float e2 = expf(-2.0f * wq * wq);
        float var = 0.5f - 0.5f * e2 * cosf(2.0f * ph) - mean * mean;
        float r = 1.0f / sqrtf(1e-3f + var);
        wrev_sh[t] = wq * 0.15915494309189535f;   // /2pi -> revolutions for v_sin
        prev_sh[t] = ph * 0.15915494309189535f;
        r_sh[t] = r;
        m_sh[t] = mean;
    }
    // sl[n] = sum_i lamb[i][n0+n], split over 2 halves of i
    {
        int n = t & 127, half = t >> 7;
        float s = 0.f;
        const float* lp = lamb + (size_t)(half * 256) * O + n0 + n;
        #pragma unroll 8
        for (int i = 0; i < 256; ++i) s += lp[(size_t)i * O];
        slp_sh[half][n] = s;
    }
    __syncthreads();
    // brP[f][c][w] = beta[f][n0 + w*16 + c] * r_f   (bf16)
    #pragma unroll
    for (int j = 0; j < 32; ++j) {
        int e = t + TB * j;          // 0..8191
        int f = e >> 7;              // 0..63
        int rem = e & 127;
        int w = rem >> 4;            // 0..7
        int c = rem & 15;
        float bv = beta[f * O + n0 + w * 16 + c] * r_sh[f];
        brP_sh[f][c][w] = f_to_bf16u(bv);
    }
    __syncthreads();
    if (t < BN) {
        int c = t & 15, w = t >> 4;
        float sb = 0.f;
        #pragma unroll
        for (int f = 0; f < F; ++f) sb += bf16u_to_f(brP_sh[f][c][w]) * m_sh[f];
        c_sh[t] = bias[n0 + t] - sb * (slp_sh[0][t] + slp_sh[1][t]);
    }

    // ---- wave geometry: wave wid owns rows [m0+16*wid, +16), all 128 cols ----
    const int lane = t & 63;
    const int wid  = t >> 6;
    const int l15  = lane & 15;
    const int quad = lane >> 4;
    const int row  = m0 + wid * 16 + l15;

    floatx4 oacc[8];
    #pragma unroll
    for (int nt = 0; nt < 8; ++nt) oacc[nt] = (floatx4){0.f, 0.f, 0.f, 0.f};
    const floatx4 zero4 = (floatx4){0.f, 0.f, 0.f, 0.f};

    #pragma unroll 1
    for (int it = 0; it < 8; ++it) {
        const int i0 = it * 64;
        // lambda tile -> LDS (bf16), once per i-tile (verbatim round-0).
        // Protected by the f=63 barrier of the previous i-tile (round-0 cadence).
        {
            int n  = t & 127;
            int kh = t >> 7;           // 0..1
            const float* lp = lamb + (size_t)(i0 + kh * 32) * O + n0 + n;
            float v[32];
            #pragma unroll
            for (int k = 0; k < 32; ++k) v[k] = lp[(size_t)k * O];
            #pragma unroll
            for (int rr = 0; rr < 4; ++rr) {
                uintx4 w4;
                w4.x = pk_bf16(v[rr*8+0], v[rr*8+1]);
                w4.y = pk_bf16(v[rr*8+2], v[rr*8+3]);
                w4.z = pk_bf16(v[rr*8+4], v[rr*8+5]);
                w4.w = pk_bf16(v[rr*8+6], v[rr*8+7]);
                *(uintx4*)&L_sh[n][kh * 32 + rr * 8] = w4;
            }
        }
        // x -> regs: exactly the 16 values this lane's A-frags need.
        // xr0[j] = x[row][i0 + quad*8 + j], xr1[j] = x[row][i0 + 32 + quad*8 + j]
        float xr0[8], xr1[8];
        {
            const float* xp = x + (size_t)row * I + i0 + quad * 8;
            float4 a0 = *(const float4*)(xp);
            float4 a1 = *(const float4*)(xp + 4);
            float4 b0 = *(const float4*)(xp + 32);
            float4 b1 = *(const float4*)(xp + 36);
            xr0[0]=a0.x; xr0[1]=a0.y; xr0[2]=a0.z; xr0[3]=a0.w;
            xr0[4]=a1.x; xr0[5]=a1.y; xr0[6]=a1.z; xr0[7]=a1.w;
            xr1[0]=b0.x; xr1[1]=b0.y; xr1[2]=b0.z; xr1[3]=b0.w;
            xr1[4]=b1.x; xr1[5]=b1.y; xr1[6]=b1.z; xr1[7]=b1.w;
        }
        // A fragments for f=0 (registers)
        short8 af0 = sin_frag8(xr0, wrev_sh[0], prev_sh[0]);
        short8 af1 = sin_frag8(xr1, wrev_sh[0], prev_sh[0]);
        __syncthreads();   // L_sh ready
        // lambda fragments (f-invariant within this i-tile) -> registers
        short8 lf[2][8];
        #pragma unroll
        for (int kk = 0; kk < 2; ++kk)
            #pragma unroll
            for (int nt = 0; nt < 8; ++nt)
                lf[kk][nt] = *(const short8*)&L_sh[nt*16 + l15][kk*32 + quad*8];

        // ---- f-loop, round-0 cadence: sin(f+1) overlaps MFMA(f), barrier per f ----
        #pragma unroll 2
        for (int f = 0; f < F; ++f) {
            // betaR values for f (8 columns per lane), bf16 b64 reads (round-0 path)
            ushort4t bru0 = *(const ushort4t*)&brP_sh[f][l15][0];
            ushort4t bru1 = *(const ushort4t*)&brP_sh[f][l15][4];
            float br[8];
            #pragma unroll
            for (int q = 0; q < 4; ++q) {
                br[q]     = bf16u_to_f(bru0[q]);
                br[4 + q] = bf16u_to_f(bru1[q]);
            }
            // overlap: compute sin fragments for f+1 (registers, no staging)
            short8 nf0 = af0, nf1 = af1;
            if (f < F - 1) {
                float wfr = wrev_sh[f + 1], pfr = prev_sh[f + 1];
                nf0 = sin_frag8(xr0, wfr, pfr);
                nf1 = sin_frag8(xr1, wfr, pfr);
            }
            // S_f = A_f @ Lambda ; out += betaR (.) S_f
            #pragma unroll
            for (int nt = 0; nt < 8; ++nt) {
                floatx4 s = __builtin_amdgcn_mfma_f32_16x16x32_bf16(
                    af0, lf[0][nt], zero4, 0, 0, 0);
                s = __builtin_amdgcn_mfma_f32_16x16x32_bf16(
                    af1, lf[1][nt], s, 0, 0, 0);
                oacc[nt] += br[nt] * s;
            }
            __syncthreads();
            af0 = nf0; af1 = nf1;
        }
    }

    // ---- epilogue: add per-column constant, store fp32 ----
    #pragma unroll
    for (int nt = 0; nt < 8; ++nt) {
        int gn = n0 + nt*16 + l15;
        float cv = c_sh[nt*16 + l15];
        int gm = m0 + wid*16 + quad*4;
        #pragma unroll
        for (int rg = 0; rg < 4; ++rg) {
            out[(size_t)(gm + rg) * O + gn] = oacc[nt][rg] + cv;
        }
    }
}

extern "C" void kernel_launch(void* const* d_in, const int* in_sizes, int n_in,
                              void* d_out, int out_size, void* d_ws, size_t ws_size,
                              hipStream_t stream) {
    const float* x      = (const float*)d_in[0];
    const float* freqs  = (const float*)d_in[1];
    const float* phases = (const float*)d_in[2];
    const float* beta   = (const float*)d_in[3];
    const float* lamb   = (const float*)d_in[4];
    const float* bias   = (const float*)d_in[5];
    float* out = (float*)d_out;

    dim3 grid(512);   // (8192/64) m-blocks * (512/128) n-blocks
    dim3 block(TB);
    hipLaunchKernelGGL(actlayer_kernel, grid, block, 0, stream,
                       x, freqs, phases, beta, lamb, bias, out);
}